// Round 2
// baseline (1700.872 us; speedup 1.0000x reference)
//
#include <hip/hip_runtime.h>
#include <cstddef>

// AttentionLayerPooler: out[m,n] = sum_l softmax(logits)[m,l] * in[l,n]
// for in = ks and vs separately. L_TEACHER=36, L_STUDENT=28,
// per-layer slice = B*H*S*D = 2,097,152 fp32.
// Memory-bound: ~1.07 GB kernel-view traffic -> ~170 us floor @ 6.3 TB/s.
// R1 was latency-bound (occupancy 21%, VALUBusy 23%, HBM 29%).
// R2: register double-buffer prefetch + __launch_bounds__(256,3).

constexpr int LT = 36;                      // teacher layers
constexpr int LS = 28;                      // student layers
constexpr int NELEM = 1 * 16 * 1024 * 128;  // elements per layer slice
constexpr int N4 = NELEM / 4;               // float4 columns per layer (524288)
constexpr int TPB = 256;
constexpr int BLOCKS_PER_TENSOR = N4 / TPB; // 2048 (power of two)

__device__ __forceinline__ void fma4(float4& a, float w, const float4& v) {
    a.x = fmaf(w, v.x, a.x);
    a.y = fmaf(w, v.y, a.y);
    a.z = fmaf(w, v.z, a.z);
    a.w = fmaf(w, v.w, a.w);
}

// launch_bounds(256, 3): min 3 waves/EU -> VGPR cap 170. Need ~155
// (112 acc + 32 dbuf + addr), so no spill; guarantees 12 waves/CU.
__global__ __launch_bounds__(TPB, 3) void pool_kernel(
    const float4* __restrict__ ks,
    const float4* __restrict__ vs,
    const float* __restrict__ lgk,
    const float* __restrict__ lgv,
    float4* __restrict__ out)
{
    // Per-block softmax of the 28x36 weight matrix into LDS (broadcast reads,
    // no bank conflicts; redundant per-block compute is negligible vs 260 KB
    // of HBM traffic per block).
    __shared__ __align__(16) float wl[LS][LT];

    const bool is_v = (blockIdx.x >= BLOCKS_PER_TENSOR);
    const float* lg = is_v ? lgv : lgk;
    const float4* src = is_v ? vs : ks;
    float4* dst = out + (is_v ? (size_t)LS * N4 : (size_t)0);

    const int tid = threadIdx.x;
    if (tid < LS) {
        const float* row = lg + tid * LT;
        float mx = -3.4e38f;
        for (int l = 0; l < LT; ++l) mx = fmaxf(mx, row[l]);
        float s = 0.f;
        for (int l = 0; l < LT; ++l) s += expf(row[l] - mx);
        const float inv = 1.0f / s;
        for (int l = 0; l < LT; ++l) wl[tid][l] = expf(row[l] - mx) * inv;
    }
    __syncthreads();

    // Each thread owns one float4 column; loads each input element exactly
    // once, accumulates all 28 outputs in registers.
    const int n4 = (blockIdx.x & (BLOCKS_PER_TENSOR - 1)) * TPB + tid;
    const float4* p = src + n4;

    float4 acc[LS];
#pragma unroll
    for (int m = 0; m < LS; ++m) acc[m] = make_float4(0.f, 0.f, 0.f, 0.f);

    // Software pipeline: register double-buffer over groups of 4 layers.
    // The next group's 4 loads (4 KB/wave) are issued BEFORE the current
    // 448-FMA block (~900 cyc at wave64), hiding one full HBM latency.
    float4 c0 = p[0];
    float4 c1 = p[(size_t)1 * N4];
    float4 c2 = p[(size_t)2 * N4];
    float4 c3 = p[(size_t)3 * N4];

#pragma unroll
    for (int lb = 0; lb < LT / 4; ++lb) {
        float4 n0, n1, n2, n3;
        if (lb + 1 < LT / 4) {
            const float4* pn = p + (size_t)(4 * (lb + 1)) * N4;
            n0 = pn[0];
            n1 = pn[(size_t)1 * N4];
            n2 = pn[(size_t)2 * N4];
            n3 = pn[(size_t)3 * N4];
        }
#pragma unroll
        for (int m = 0; m < LS; ++m) {
            const float4 w = *reinterpret_cast<const float4*>(&wl[m][4 * lb]);
            fma4(acc[m], w.x, c0);
            fma4(acc[m], w.y, c1);
            fma4(acc[m], w.z, c2);
            fma4(acc[m], w.w, c3);
        }
        if (lb + 1 < LT / 4) { c0 = n0; c1 = n1; c2 = n2; c3 = n3; }
    }

    float4* q = dst + n4;
#pragma unroll
    for (int m = 0; m < LS; ++m) q[(size_t)m * N4] = acc[m];
}

extern "C" void kernel_launch(void* const* d_in, const int* in_sizes, int n_in,
                              void* d_out, int out_size, void* d_ws, size_t ws_size,
                              hipStream_t stream)
{
    const float4* ks  = (const float4*)d_in[0];
    const float4* vs  = (const float4*)d_in[1];
    const float* lgk  = (const float*)d_in[2];
    const float* lgv  = (const float*)d_in[3];
    float4* out = (float4*)d_out;

    dim3 grid(2 * BLOCKS_PER_TENSOR);
    dim3 block(TPB);
    hipLaunchKernelGGL(pool_kernel, grid, block, 0, stream,
                       ks, vs, lgk, lgv, out);
}

// Round 3
// 753.813 us; speedup vs baseline: 2.2564x; 2.2564x over previous
//
#include <hip/hip_runtime.h>
#include <cstddef>

// AttentionLayerPooler: out[m,n] = sum_l softmax(logits)[m,l] * in[l,n]
// for in = ks and vs separately. L_TEACHER=36, L_STUDENT=28,
// per-layer slice = B*H*S*D = 2,097,152 fp32.
// Ideal traffic ~1.07 GB -> ~170 us floor @ 6.3 TB/s.
//
// R1 (float4 cols, 28 float4 accs): 285 us. 100 VGPR + ~112 AGPR parked
//    accumulators -> 2 waves/SIMD, occupancy 21%, latency-bound at 2.3 TB/s.
// R2 (launch_bounds(256,3)): cap 170 combined < working set -> scratch
//    spill, 6.2 GB traffic, 1700 us. Lesson: shrink the working set,
//    don't squeeze the allocator.
// R3: float2 columns -> acc = 56 VGPRs. Working set ~100-115 regs fits a
//    safe (256,4) cap of 128 -> 4 waves/SIMD, traffic still ideal.

constexpr int LT = 36;                      // teacher layers
constexpr int LS = 28;                      // student layers
constexpr int NELEM = 1 * 16 * 1024 * 128;  // elements per layer slice
constexpr int N2 = NELEM / 2;               // float2 columns per layer (1048576)
constexpr int TPB = 256;
constexpr int BLOCKS_PER_TENSOR = N2 / TPB; // 4096 (power of two)

__device__ __forceinline__ void fma2(float2& a, float w, const float2& v) {
    a.x = fmaf(w, v.x, a.x);
    a.y = fmaf(w, v.y, a.y);
}

// (256,4): 4 blocks/CU = 4 waves/SIMD, combined VGPR+AGPR cap = 128.
// Working set ~100-115 -> fits without spill (R2's mistake was 170 vs 155).
__global__ __launch_bounds__(TPB, 4) void pool_kernel(
    const float2* __restrict__ ks,
    const float2* __restrict__ vs,
    const float* __restrict__ lgk,
    const float* __restrict__ lgv,
    float2* __restrict__ out)
{
    // Per-block softmax of the 28x36 weight matrix into LDS (broadcast
    // reads; redundant per-block compute is negligible vs ~130 KB HBM
    // traffic per block).
    __shared__ __align__(16) float wl[LS][LT];

    const bool is_v = (blockIdx.x >= BLOCKS_PER_TENSOR);
    const float* lg = is_v ? lgv : lgk;
    const float2* src = is_v ? vs : ks;
    float2* dst = out + (is_v ? (size_t)LS * N2 : (size_t)0);

    const int tid = threadIdx.x;
    if (tid < LS) {
        const float* row = lg + tid * LT;
        float mx = -3.4e38f;
        for (int l = 0; l < LT; ++l) mx = fmaxf(mx, row[l]);
        float s = 0.f;
        for (int l = 0; l < LT; ++l) s += expf(row[l] - mx);
        const float inv = 1.0f / s;
        for (int l = 0; l < LT; ++l) wl[tid][l] = expf(row[l] - mx) * inv;
    }
    __syncthreads();

    // Each thread owns one float2 column; loads each input element exactly
    // once, accumulates all 28 outputs in 56 VGPRs.
    const int n2 = (blockIdx.x & (BLOCKS_PER_TENSOR - 1)) * TPB + tid;
    const float2* p = src + n2;

    float2 acc[LS];
#pragma unroll
    for (int m = 0; m < LS; ++m) acc[m] = make_float2(0.f, 0.f);

    // unroll 3 -> 12 independent 8B loads (24 regs in flight) per body;
    // 4 waves/SIMD x 4 KB outstanding covers the ~9 KB/CU latency-BW
    // product comfortably.
#pragma unroll 3
    for (int lb = 0; lb < LT / 4; ++lb) {
        const float2 v0 = p[(size_t)(4 * lb + 0) * N2];
        const float2 v1 = p[(size_t)(4 * lb + 1) * N2];
        const float2 v2 = p[(size_t)(4 * lb + 2) * N2];
        const float2 v3 = p[(size_t)(4 * lb + 3) * N2];
#pragma unroll
        for (int m = 0; m < LS; ++m) {
            const float4 w = *reinterpret_cast<const float4*>(&wl[m][4 * lb]);
            fma2(acc[m], w.x, v0);
            fma2(acc[m], w.y, v1);
            fma2(acc[m], w.z, v2);
            fma2(acc[m], w.w, v3);
        }
    }

    float2* q = dst + n2;
#pragma unroll
    for (int m = 0; m < LS; ++m) q[(size_t)m * N2] = acc[m];
}

extern "C" void kernel_launch(void* const* d_in, const int* in_sizes, int n_in,
                              void* d_out, int out_size, void* d_ws, size_t ws_size,
                              hipStream_t stream)
{
    const float2* ks  = (const float2*)d_in[0];
    const float2* vs  = (const float2*)d_in[1];
    const float* lgk  = (const float*)d_in[2];
    const float* lgv  = (const float*)d_in[3];
    float2* out = (float2*)d_out;

    dim3 grid(2 * BLOCKS_PER_TENSOR);
    dim3 block(TPB);
    hipLaunchKernelGGL(pool_kernel, grid, block, 0, stream,
                       ks, vs, lgk, lgv, out);
}

// Round 4
// 291.631 us; speedup vs baseline: 5.8323x; 2.5848x over previous
//
#include <hip/hip_runtime.h>
#include <cstddef>

// AttentionLayerPooler: out[m,n] = sum_l softmax(logits)[m,l] * in[l,n]
// for in = ks and vs separately. L_TEACHER=36, L_STUDENT=28,
// per-layer slice = B*H*S*D = 2,097,152 fp32.
// Ideal traffic ~1.07 GB -> ~170 us floor @ 6.3 TB/s.
//
// R1 (float4 cols, no bound): 285 us. accs parked in AGPRs (100V+112A)
//    -> 2 waves/SIMD, occupancy 21%, latency-bound at 3.3 TB/s.
// R2 (float4, bounds(256,3)): allocator minimized to 84 regs, spilled accs
//    to scratch, 6.2 GB traffic, 1700 us.
// R3 (float2, bounds(256,4)): same failure mode (64 regs, 2.5 GB), 754 us.
//    LESSON: any min-waves launch_bounds makes hipcc spill the acc array.
// R4: float2 columns (56 acc VGPRs, working set ~100) with NO min-waves
//    bound -> compiler fits in ~110-130 regs, 4 waves/SIMD, no spill.

constexpr int LT = 36;                      // teacher layers
constexpr int LS = 28;                      // student layers
constexpr int NELEM = 1 * 16 * 1024 * 128;  // elements per layer slice
constexpr int N2 = NELEM / 2;               // float2 columns per layer (1048576)
constexpr int TPB = 256;
constexpr int BLOCKS_PER_TENSOR = N2 / TPB; // 4096 (power of two)

__device__ __forceinline__ void fma2(float2& a, float w, const float2& v) {
    a.x = fmaf(w, v.x, a.x);
    a.y = fmaf(w, v.y, a.y);
}

__global__ __launch_bounds__(TPB) void pool_kernel(
    const float2* __restrict__ ks,
    const float2* __restrict__ vs,
    const float* __restrict__ lgk,
    const float* __restrict__ lgv,
    float2* __restrict__ out)
{
    // Per-block softmax of the 28x36 weight matrix into LDS (broadcast
    // reads; redundant per-block compute is negligible vs ~130 KB HBM
    // traffic per block).
    __shared__ __align__(16) float wl[LS][LT];

    const bool is_v = (blockIdx.x >= BLOCKS_PER_TENSOR);
    const float* lg = is_v ? lgv : lgk;
    const float2* src = is_v ? vs : ks;
    float2* dst = out + (is_v ? (size_t)LS * N2 : (size_t)0);

    const int tid = threadIdx.x;
    if (tid < LS) {
        const float* row = lg + tid * LT;
        float mx = -3.4e38f;
        for (int l = 0; l < LT; ++l) mx = fmaxf(mx, row[l]);
        float s = 0.f;
        for (int l = 0; l < LT; ++l) s += expf(row[l] - mx);
        const float inv = 1.0f / s;
        for (int l = 0; l < LT; ++l) wl[tid][l] = expf(row[l] - mx) * inv;
    }
    __syncthreads();

    // Each thread owns one float2 column; loads each input element exactly
    // once, accumulates all 28 outputs in 56 VGPRs.
    const int n2 = (blockIdx.x & (BLOCKS_PER_TENSOR - 1)) * TPB + tid;
    const float2* p = src + n2;

    float2 acc[LS];
#pragma unroll
    for (int m = 0; m < LS; ++m) acc[m] = make_float2(0.f, 0.f);

    // unroll 3 -> 12 independent 8B loads in flight per body; per 4-layer
    // group the FMA block (224 FMAs = 448 issue-cycles) dominates the
    // 28 ds_read_b128 weight reads (~336 cyc), so VALU stays the critical
    // pipe and loads hide under it.
#pragma unroll 3
    for (int lb = 0; lb < LT / 4; ++lb) {
        const float2 v0 = p[(size_t)(4 * lb + 0) * N2];
        const float2 v1 = p[(size_t)(4 * lb + 1) * N2];
        const float2 v2 = p[(size_t)(4 * lb + 2) * N2];
        const float2 v3 = p[(size_t)(4 * lb + 3) * N2];
#pragma unroll
        for (int m = 0; m < LS; ++m) {
            const float4 w = *reinterpret_cast<const float4*>(&wl[m][4 * lb]);
            fma2(acc[m], w.x, v0);
            fma2(acc[m], w.y, v1);
            fma2(acc[m], w.z, v2);
            fma2(acc[m], w.w, v3);
        }
    }

    float2* q = dst + n2;
#pragma unroll
    for (int m = 0; m < LS; ++m) q[(size_t)m * N2] = acc[m];
}

extern "C" void kernel_launch(void* const* d_in, const int* in_sizes, int n_in,
                              void* d_out, int out_size, void* d_ws, size_t ws_size,
                              hipStream_t stream)
{
    const float2* ks  = (const float2*)d_in[0];
    const float2* vs  = (const float2*)d_in[1];
    const float* lgk  = (const float*)d_in[2];
    const float* lgv  = (const float*)d_in[3];
    float2* out = (float2*)d_out;

    dim3 grid(2 * BLOCKS_PER_TENSOR);
    dim3 block(TPB);
    hipLaunchKernelGGL(pool_kernel, grid, block, 0, stream,
                       ks, vs, lgk, lgv, out);
}

// Round 5
// 228.980 us; speedup vs baseline: 7.4280x; 1.2736x over previous
//
#include <hip/hip_runtime.h>
#include <cstddef>

// AttentionLayerPooler: out[m,n] = sum_l softmax(logits)[m,l] * in[l,n]
// for in = ks and vs separately. LT=36, LS=28, slice = 2,097,152 fp32.
// Ideal traffic ~1.07 GB -> ~170 us floor @ 6.3 TB/s.
//
// R1 (float4 cols, reg accs): 285 us. 2 blocks/CU (combined VGPR+AGPR),
//    occupancy 21%, latency-bound at ~2.3-3.3 TB/s.
// R2/R3 (launch_bounds min-waves): allocator spills acc array to scratch,
//    4-6x traffic. NEVER use a min-waves bound with a big acc array.
// R4 (float2 cols): no spill but occupancy STILL 21% -> compiler parks
//    accs/in-flight loads in AGPRs; reg-resident-acc structure is stuck.
// R5: LDS-staged tile. global_load_lds (width=16) stages 36 layers x
//    128 float2 cols (36 KB) with ZERO register cost; compute reads LDS.
//    Acc = 7 m/wave x 2 cols = 28 VGPRs. 40.9 KB LDS -> 4 blocks/CU.

constexpr int LT = 36;                      // teacher layers
constexpr int LS = 28;                      // student layers
constexpr int NELEM = 1 * 16 * 1024 * 128;  // elements per layer slice
constexpr int N2 = NELEM / 2;               // float2 cols per layer (1048576)
constexpr int TILE = 128;                   // float2 cols per block tile
constexpr int TPB = 256;                    // 4 waves
constexpr int BLOCKS_PER_TENSOR = N2 / TILE; // 8192

__global__ __launch_bounds__(TPB) void pool_kernel(
    const float2* __restrict__ ks,
    const float2* __restrict__ vs,
    const float* __restrict__ lgk,
    const float* __restrict__ lgv,
    float2* __restrict__ out)
{
    // Staged input tile: [layer][col], linear layout (global_load_lds writes
    // wave-uniform base + lane*16, which matches [l][128 float2] exactly).
    __shared__ float2 sm[LT][TILE];
    // Softmax weights, original [m][l] orientation; rows are 144 B so
    // float4 reads at l%4==0 are 16B-aligned.
    __shared__ __align__(16) float wl[LS][LT];

    const int tid  = threadIdx.x;
    const int wv   = tid >> 6;        // wave 0..3
    const int lane = tid & 63;

    const bool is_v = (blockIdx.x >= BLOCKS_PER_TENSOR);
    const float* lg = is_v ? lgv : lgk;
    const float2* src = is_v ? vs : ks;
    float2* dst = out + (is_v ? (size_t)LS * N2 : (size_t)0);
    const int c0 = (blockIdx.x & (BLOCKS_PER_TENSOR - 1)) * TILE;

    // --- Stage: wave wv loads layers 9*wv .. 9*wv+8, 1 KB each, directly
    // to LDS. No VGPR round-trip; 9 instructions/wave. Issue FIRST so the
    // HBM burst overlaps the softmax below.
#pragma unroll
    for (int j = 0; j < 9; ++j) {
        const int l = 9 * wv + j;
        const float2* g = src + (size_t)l * N2 + c0 + 2 * lane; // 16 B/lane
        __builtin_amdgcn_global_load_lds(
            (const __attribute__((address_space(1))) void*)g,
            (__attribute__((address_space(3))) void*)&sm[l][0],
            16, 0, 0);
    }

    // --- Softmax of the 28x36 logit rows (overlaps in-flight loads).
    if (tid < LS) {
        const float* row = lg + tid * LT;
        float mx = -3.4e38f;
        for (int l = 0; l < LT; ++l) mx = fmaxf(mx, row[l]);
        float s = 0.f;
        for (int l = 0; l < LT; ++l) s += expf(row[l] - mx);
        const float inv = 1.0f / s;
        for (int l = 0; l < LT; ++l) wl[tid][l] = expf(row[l] - mx) * inv;
    }
    __syncthreads();  // drains vmcnt(0) for the lds-loads + orders wl

    // --- Compute: wave wv owns m in [7*wv, 7*wv+7); lane owns cols
    // lane and lane+64. acc = 28 VGPRs.
    const int m0 = 7 * wv;
    float2 acc[7][2];
#pragma unroll
    for (int k = 0; k < 7; ++k) {
        acc[k][0] = make_float2(0.f, 0.f);
        acc[k][1] = make_float2(0.f, 0.f);
    }

#pragma unroll
    for (int lb = 0; lb < LT / 4; ++lb) {
        // 8 ds_read_b64, contiguous per wave -> conflict-free
        float2 d0[4], d1[4];
#pragma unroll
        for (int j = 0; j < 4; ++j) {
            d0[j] = sm[4 * lb + j][lane];
            d1[j] = sm[4 * lb + j][lane + 64];
        }
#pragma unroll
        for (int k = 0; k < 7; ++k) {
            // broadcast ds_read_b128 (same addr across wave -> free)
            const float4 w = *reinterpret_cast<const float4*>(&wl[m0 + k][4 * lb]);
            acc[k][0].x = fmaf(w.x, d0[0].x, acc[k][0].x);
            acc[k][0].y = fmaf(w.x, d0[0].y, acc[k][0].y);
            acc[k][1].x = fmaf(w.x, d1[0].x, acc[k][1].x);
            acc[k][1].y = fmaf(w.x, d1[0].y, acc[k][1].y);
            acc[k][0].x = fmaf(w.y, d0[1].x, acc[k][0].x);
            acc[k][0].y = fmaf(w.y, d0[1].y, acc[k][0].y);
            acc[k][1].x = fmaf(w.y, d1[1].x, acc[k][1].x);
            acc[k][1].y = fmaf(w.y, d1[1].y, acc[k][1].y);
            acc[k][0].x = fmaf(w.z, d0[2].x, acc[k][0].x);
            acc[k][0].y = fmaf(w.z, d0[2].y, acc[k][0].y);
            acc[k][1].x = fmaf(w.z, d1[2].x, acc[k][1].x);
            acc[k][1].y = fmaf(w.z, d1[2].y, acc[k][1].y);
            acc[k][0].x = fmaf(w.w, d0[3].x, acc[k][0].x);
            acc[k][0].y = fmaf(w.w, d0[3].y, acc[k][0].y);
            acc[k][1].x = fmaf(w.w, d1[3].x, acc[k][1].x);
            acc[k][1].y = fmaf(w.w, d1[3].y, acc[k][1].y);
        }
    }

    // --- Store: 14 coalesced dwordx2 per lane.
#pragma unroll
    for (int k = 0; k < 7; ++k) {
        float2* q = dst + (size_t)(m0 + k) * N2 + c0;
        q[lane]      = acc[k][0];
        q[lane + 64] = acc[k][1];
    }
}

extern "C" void kernel_launch(void* const* d_in, const int* in_sizes, int n_in,
                              void* d_out, int out_size, void* d_ws, size_t ws_size,
                              hipStream_t stream)
{
    const float2* ks  = (const float2*)d_in[0];
    const float2* vs  = (const float2*)d_in[1];
    const float* lgk  = (const float*)d_in[2];
    const float* lgv  = (const float*)d_in[3];
    float2* out = (float2*)d_out;

    dim3 grid(2 * BLOCKS_PER_TENSOR);
    dim3 block(TPB);
    hipLaunchKernelGGL(pool_kernel, grid, block, 0, stream,
                       ks, vs, lgk, lgv, out);
}